// Round 5
// baseline (372.608 us; speedup 1.0000x reference)
//
#include <hip/hip_runtime.h>

// TemporalLogicLayer R5: R4 + fix of the L1' PW-row clamp.
// out[b,t,o] = max_{s>=t} sigmoid(5*(relu(relu([cummax(P[t..s])|P[s]]W1+b1)W2+b2)W3+b3))
//
// R4 bug: rowg = min(s0*32+row, 4095) mapped out-of-range (s,b) to (127,31) —
// wrong batch — and R4's unconditional z-merge (which assumes clamped rows
// duplicate the SAME batch's s=127 row) then folded garbage in. Fix: clamp s
// only, preserve b:  rowg = min(s0 + (row>>5), 127)*32 + (row&31).
//
// Structure (from R4):
// - items (t, 4-step chunk) as contiguous t-major ranges per block; per-(b,o)
//   max kept in registers in the z-domain (sigmoid monotone), flushed by
//   atomicMax only on t-change.
// - W1/W2 read from L2-warm global (A-operand); LDS = hS + cmx = 75776 B ->
//   2 blocks/CU, 4 waves/SIMD, __launch_bounds__(512,4).
// - preps: merged weights+sparse-table kernel (272 blocks), PW builder (64).

#define TT 128
#define BB 32
#define DD 128
#define OO 64
#define NP 144
#define HSTR 168
#define N_ITEMS 2112

typedef __attribute__((ext_vector_type(8))) _Float16 half8;
typedef __attribute__((ext_vector_type(4))) _Float16 half4;
typedef __attribute__((ext_vector_type(4))) float f32x4;

// ws layout (bytes)
#define W1T_OFF 0                                   // f16 [144][256]
#define W2T_OFF (W1T_OFF + 144*256*2)               // f16 [144][160]
#define W3T_OFF (W2T_OFF + 144*160*2)               // f16 [64][160]
#define B1P_OFF (W3T_OFF + 64*160*2)                // f32 [144]
#define B2P_OFF (B1P_OFF + 144*4)                   // f32 [144]
#define PW_OFF  (B2P_OFF + 144*4)                   // f16 [4096][144]
#define TAB_OFF (PW_OFF + 4096*144*2)               // f16 [5][128][32][128]

#define MFMA(A, B, C) __builtin_amdgcn_mfma_f32_16x16x32_f16((A), (B), (C), 0, 0, 0)

__device__ __forceinline__ half8 h8max(half8 a, half8 b) {
    half8 r;
    #pragma unroll
    for (int i = 0; i < 8; ++i) r[i] = (a[i] > b[i]) ? a[i] : b[i];
    return r;
}

// ---------- prep A (272 blocks): weights transpose + sparse max table ----------
__global__ void tll_prep_wt(const float* __restrict__ P,
                            const float* __restrict__ W1, const float* __restrict__ b1,
                            const float* __restrict__ W2, const float* __restrict__ b2,
                            const float* __restrict__ W3, char* __restrict__ ws) {
    __shared__ _Float16 tb[2][128 * 32];            // 16 KB (tab part only)
    const int blk = blockIdx.x, tid = threadIdx.x;
    if (blk < 144) {
        _Float16* W1t = (_Float16*)(ws + W1T_OFF);
        _Float16* W2t = (_Float16*)(ws + W2T_OFF);
        _Float16* W3t = (_Float16*)(ws + W3T_OFF);
        float*    b1p = (float*)(ws + B1P_OFF);
        float*    b2p = (float*)(ws + B2P_OFF);
        int idx = blk * 256 + tid;
        if (idx < 144*256) {                        // W1t[n][k] = W1[k][n]
            int n = idx >> 8, k = idx & 255;
            W1t[idx] = (_Float16)((n < 132) ? W1[k*132 + n] : 0.f);
        }
        if (idx < 144*160) {                        // W2t[n][k] = W2[k][n]
            int n = idx / 160, k = idx - n*160;
            W2t[idx] = (_Float16)((n < 132 && k < 132) ? W2[k*132 + n] : 0.f);
        }
        if (idx < 64*160) {                         // W3t[o][k] = W3[k][o]
            int o = idx / 160, k = idx - o*160;
            W3t[idx] = (_Float16)((k < 132) ? W3[k*64 + o] : 0.f);
        }
        if (idx < 144) {
            b1p[idx] = (idx < 132) ? b1[idx] : 0.f;
            b2p[idx] = (idx < 132) ? b2[idx] : 0.f;
        }
    } else {
        const int bb = blk - 144;                   // 128 blocks: (b, d-quarter)
        const int b = bb >> 2, d0 = (bb & 3) * 32;
        _Float16* TAB = (_Float16*)(ws + TAB_OFF);
        for (int i = tid; i < 4096; i += 256)
            tb[0][i] = (_Float16)P[b*(TT*DD) + (i >> 5)*DD + d0 + (i & 31)];
        __syncthreads();
        for (int i = tid; i < 4096; i += 256) {     // level 0: window 4
            int t = i >> 5, di = i & 31;
            _Float16 v = tb[0][i];
            #pragma unroll
            for (int dt = 1; dt < 4; ++dt) {
                int s = t + dt; if (s > 127) s = 127;
                _Float16 u = tb[0][s*32 + di];
                v = (u > v) ? u : v;
            }
            tb[1][i] = v;
            TAB[t*4096 + b*128 + d0 + di] = v;
        }
        __syncthreads();
        int src = 1;
        for (int lev = 1; lev < 5; ++lev) {         // windows 8,16,32,64
            int shift = 1 << (lev + 1);
            for (int i = tid; i < 4096; i += 256) {
                int t = i >> 5, di = i & 31;
                int s = t + shift; if (s > 127) s = 127;
                _Float16 a = tb[src][i], c = tb[src][s*32 + di];
                _Float16 v = (c > a) ? c : a;
                tb[src ^ 1][i] = v;
                TAB[(size_t)lev*524288 + t*4096 + b*128 + d0 + di] = v;
            }
            __syncthreads();
            src ^= 1;
        }
    }
}

// ---------- prep B (64 blocks): PW[row][n] = P[row] @ W1[128:256,:] ----------
__global__ void tll_prep_pw(const float* __restrict__ P, char* __restrict__ ws) {
    const _Float16* W1t = (const _Float16*)(ws + W1T_OFF);
    _Float16* PW = (_Float16*)(ws + PW_OFF);
    const int tid = threadIdx.x, w = tid >> 6, lane = tid & 63;
    const int ln = lane & 15, q = lane >> 4;
    const int row = (blockIdx.x*4 + w)*16 + ln;     // 0..4095
    const int b_ = row & 31, s_ = row >> 5;
    const float* pp = P + b_*(TT*DD) + s_*DD;
    half8 Bf[4];
    #pragma unroll
    for (int kst = 0; kst < 4; ++kst) {
        f32x4 p0 = *(const f32x4*)(pp + kst*32 + q*8);
        f32x4 p1 = *(const f32x4*)(pp + kst*32 + q*8 + 4);
        half8 h;
        #pragma unroll
        for (int i = 0; i < 4; ++i) { h[i] = (_Float16)p0[i]; h[4+i] = (_Float16)p1[i]; }
        Bf[kst] = h;
    }
    for (int mt = 0; mt < 9; ++mt) {
        f32x4 acc = (f32x4){0.f, 0.f, 0.f, 0.f};
        #pragma unroll
        for (int kst = 0; kst < 4; ++kst) {
            half8 A = *(const half8*)(W1t + (mt*16 + ln)*256 + 128 + kst*32 + q*8);
            acc = MFMA(A, Bf[kst], acc);
        }
        half4 hv;
        #pragma unroll
        for (int i = 0; i < 4; ++i) hv[i] = (_Float16)acc[i];
        *(half4*)(PW + (size_t)row*NP + mt*16 + q*4) = hv;
    }
}

// ---------- main ----------
__global__ __launch_bounds__(512, 4) void tll_main(
    const float* __restrict__ P, const float* __restrict__ b3,
    const char* __restrict__ ws, unsigned int* __restrict__ outU)
{
    extern __shared__ char smem[];
    _Float16* hS  = (_Float16*)smem;                // [128][168] = 43008 B
    _Float16* cmx = hS + 128*HSTR;                  // [128][128] swizzled, 32768 B

    const _Float16* W1t = (const _Float16*)(ws + W1T_OFF);
    const _Float16* W2t = (const _Float16*)(ws + W2T_OFF);
    const _Float16* W3t = (const _Float16*)(ws + W3T_OFF);
    const float*    b1p = (const float*)(ws + B1P_OFF);
    const float*    b2p = (const float*)(ws + B2P_OFF);
    const _Float16* PW  = (const _Float16*)(ws + PW_OFF);
    const _Float16* TAB = (const _Float16*)(ws + TAB_OFF);

    const int tid = threadIdx.x, w = tid >> 6, lane = tid & 63;
    const int ln = lane & 15, q = lane >> 4;
    const int fg = w >> 1, rg = w & 1;              // 4 f-groups x 2 r-groups
    const bool has3 = (fg == 0);                    // f-tiles (3,2,2,2) of 9
    const int fb = (fg == 0) ? 0 : (16 + 32*fg);    // 0,48,80,112
    const int f0A = fb, f0B = fb + 16, f0C = fb + 32;
    const int og = fg, rg3 = rg;                    // L3: o-tile, j-group

    // zero hS cols 144..159 (K=144..159 read by L2'/L3'; paired W rows are 0,
    // but LDS garbage could be NaN -> keep a real zero strip)
    for (int idx = tid; idx < 256; idx += 512) {
        int row = idx >> 1, hv = idx & 1;
        half8 z;
        #pragma unroll
        for (int i = 0; i < 8; ++i) z[i] = (_Float16)0.f;
        *(half8*)(hS + row*HSTR + 144 + hv*8) = z;
    }

    const int sb = tid >> 4, dblk = tid & 15, d0 = dblk*8;  // staging role

    const int bid = blockIdx.x;
    int it = (bid*33) >> 2;                          // contiguous t-major ranges
    const int hi = ((bid + 1)*33) >> 2;

    int cur_t = -1;
    f32x4 rz0 = (f32x4){-1e30f,-1e30f,-1e30f,-1e30f};  // z-domain max, b=ln
    f32x4 rz1 = rz0;                                    // b=16+ln
    __syncthreads();

    for (; it < hi; ++it) {
        // ---- decode item -> (t, c) ----
        int g = (int)((65.0f - sqrtf((float)(4225 - 2*it))) * 0.5f);
        if (g < 0) g = 0; if (g > 31) g = 31;
        while (g > 0 && 2*g*(65 - g) > it) --g;
        while (2*(g+1)*(65 - (g+1)) <= it) ++g;
        int rem = it - 2*g*(65 - g);
        int ntc = 32 - g;
        int t  = 4*g + rem/ntc;
        int c  = rem - (rem/ntc)*ntc;
        int s0 = t + 4*c;

        // ---- flush on t-change (registers thread-private: no sync needed) ----
        if (t != cur_t) {
            if (cur_t >= 0) {
                #pragma unroll
                for (int i = 0; i < 4; ++i) {
                    float yA = 1.f / (1.f + __expf(-5.f * rz0[i]));
                    float yB = 1.f / (1.f + __expf(-5.f * rz1[i]));
                    int o = og*16 + q*4 + i;
                    atomicMax(&outU[(size_t)ln*(TT*OO) + cur_t*OO + o], __float_as_uint(yA));
                    atomicMax(&outU[(size_t)(16+ln)*(TT*OO) + cur_t*OO + o], __float_as_uint(yB));
                }
            }
            cur_t = t;
            rz0 = (f32x4){-1e30f,-1e30f,-1e30f,-1e30f};
            rz1 = rz0;
        }

        // ---- stage cmx: init from sparse table, fold 4 steps ----
        {
            half8 mi;
            if (c == 0) {
                #pragma unroll
                for (int i = 0; i < 8; ++i) mi[i] = (_Float16)(-65504.0f);
            } else {
                int L = 4*c;
                int klev = 31 - __builtin_clz(L);
                int t2 = s0 - (1 << klev);
                const _Float16* tb = TAB + (size_t)(klev - 2)*524288;
                half8 x = *(const half8*)(tb + t*4096 + sb*128 + d0);
                half8 y = *(const half8*)(tb + t2*4096 + sb*128 + d0);
                mi = h8max(x, y);
            }
            const float* pb = P + sb*(TT*DD) + d0;
            #pragma unroll
            for (int j = 0; j < 4; ++j) {
                int s = s0 + j; if (s > 127) s = 127;   // duplicates valid s=127, same b
                f32x4 p0 = *(const f32x4*)(pb + s*DD);
                f32x4 p1 = *(const f32x4*)(pb + s*DD + 4);
                half8 ph;
                #pragma unroll
                for (int i = 0; i < 4; ++i) { ph[i] = (_Float16)p0[i]; ph[4+i] = (_Float16)p1[i]; }
                mi = h8max(mi, ph);
                int row = j*32 + sb;
                *(half8*)(cmx + row*128 + ((dblk ^ (row & 15))*8)) = mi;
            }
        }
        __syncthreads();                             // [A]

        // ---- L1': z1^T = W1a^T @ cmx^T, init = PW + b1, relu -> hS ----
        {
            const f32x4 bA1 = *(const f32x4*)(b1p + f0A + q*4);
            const f32x4 bB1 = *(const f32x4*)(b1p + f0B + q*4);
            f32x4 aA[4], aB[4], aC[4];
            #pragma unroll
            for (int rj = 0; rj < 4; ++rj) {
                int row = (rg*4 + rj)*16 + ln;           // M-row: j = row>>5, b = row&31
                int sj = s0 + (row >> 5);                // FIX (R4 bug): clamp s ONLY,
                if (sj > 127) sj = 127;                  // preserve batch bits
                int rowg = sj*32 + (row & 31);
                const _Float16* pwp = PW + (size_t)rowg*NP;
                half4 pA = *(const half4*)(pwp + f0A + q*4);
                half4 pB = *(const half4*)(pwp + f0B + q*4);
                aA[rj] = bA1; aB[rj] = bB1;
                #pragma unroll
                for (int i = 0; i < 4; ++i) { aA[rj][i] += (float)pA[i]; aB[rj][i] += (float)pB[i]; }
                if (has3) {
                    const f32x4 bC1 = *(const f32x4*)(b1p + f0C + q*4);
                    half4 pC = *(const half4*)(pwp + f0C + q*4);
                    aC[rj] = bC1;
                    #pragma unroll
                    for (int i = 0; i < 4; ++i) aC[rj][i] += (float)pC[i];
                }
            }
            #pragma unroll
            for (int kst = 0; kst < 4; ++kst) {
                half8 wA = *(const half8*)(W1t + (f0A+ln)*256 + kst*32 + q*8);
                half8 wB = *(const half8*)(W1t + (f0B+ln)*256 + kst*32 + q*8);
                half8 wC;
                if (has3) wC = *(const half8*)(W1t + (f0C+ln)*256 + kst*32 + q*8);
                int kb = kst*4 + q;
                #pragma unroll
                for (int rj = 0; rj < 4; ++rj) {
                    int row = (rg*4 + rj)*16 + ln;
                    half8 bf = *(const half8*)(cmx + row*128 + ((kb ^ (row & 15))*8));
                    aA[rj] = MFMA(wA, bf, aA[rj]);
                    aB[rj] = MFMA(wB, bf, aB[rj]);
                    if (has3) aC[rj] = MFMA(wC, bf, aC[rj]);
                }
            }
            #pragma unroll
            for (int rj = 0; rj < 4; ++rj) {
                int row = (rg*4 + rj)*16 + ln;
                half4 hA, hB, hC;
                #pragma unroll
                for (int i = 0; i < 4; ++i) {
                    hA[i] = (_Float16)fmaxf(aA[rj][i], 0.f);
                    hB[i] = (_Float16)fmaxf(aB[rj][i], 0.f);
                }
                *(half4*)(hS + row*HSTR + f0A + q*4) = hA;
                *(half4*)(hS + row*HSTR + f0B + q*4) = hB;
                if (has3) {
                    #pragma unroll
                    for (int i = 0; i < 4; ++i) hC[i] = (_Float16)fmaxf(aC[rj][i], 0.f);
                    *(half4*)(hS + row*HSTR + f0C + q*4) = hC;
                }
            }
        }
        __syncthreads();                             // [B]

        // ---- L2': z2^T = W2^T @ h1^T, relu (held in regs until [C]) ----
        half4 h2A[4], h2B[4], h2C[4];
        {
            const f32x4 bA2 = *(const f32x4*)(b2p + f0A + q*4);
            const f32x4 bB2 = *(const f32x4*)(b2p + f0B + q*4);
            f32x4 aA[4], aB[4], aC[4];
            #pragma unroll
            for (int rj = 0; rj < 4; ++rj) {
                aA[rj] = bA2; aB[rj] = bB2;
                if (has3) aC[rj] = *(const f32x4*)(b2p + f0C + q*4);
            }
            #pragma unroll
            for (int kst = 0; kst < 5; ++kst) {
                half8 wA = *(const half8*)(W2t + (f0A+ln)*160 + kst*32 + q*8);
                half8 wB = *(const half8*)(W2t + (f0B+ln)*160 + kst*32 + q*8);
                half8 wC;
                if (has3) wC = *(const half8*)(W2t + (f0C+ln)*160 + kst*32 + q*8);
                #pragma unroll
                for (int rj = 0; rj < 4; ++rj) {
                    int row = (rg*4 + rj)*16 + ln;
                    half8 bf = *(const half8*)(hS + row*HSTR + kst*32 + q*8);
                    aA[rj] = MFMA(wA, bf, aA[rj]);
                    aB[rj] = MFMA(wB, bf, aB[rj]);
                    if (has3) aC[rj] = MFMA(wC, bf, aC[rj]);
                }
            }
            #pragma unroll
            for (int rj = 0; rj < 4; ++rj) {
                #pragma unroll
                for (int i = 0; i < 4; ++i) {
                    h2A[rj][i] = (_Float16)fmaxf(aA[rj][i], 0.f);
                    h2B[rj][i] = (_Float16)fmaxf(aB[rj][i], 0.f);
                    if (has3) h2C[rj][i] = (_Float16)fmaxf(aC[rj][i], 0.f);
                }
            }
        }
        __syncthreads();                             // [C] all h1 reads done
        #pragma unroll
        for (int rj = 0; rj < 4; ++rj) {
            int row = (rg*4 + rj)*16 + ln;
            *(half4*)(hS + row*HSTR + f0A + q*4) = h2A[rj];
            *(half4*)(hS + row*HSTR + f0B + q*4) = h2B[rj];
            if (has3) *(half4*)(hS + row*HSTR + f0C + q*4) = h2C[rj];
        }
        __syncthreads();                             // [D]

        // ---- L3': z3^T = W3^T @ h2^T; merge into register z-max ----
        {
            const f32x4 bz3 = *(const f32x4*)(b3 + og*16 + q*4);
            f32x4 z[4];
            #pragma unroll
            for (int rj = 0; rj < 4; ++rj) z[rj] = bz3;
            #pragma unroll
            for (int kst = 0; kst < 5; ++kst) {
                half8 wO = *(const half8*)(W3t + (og*16+ln)*160 + kst*32 + q*8);
                #pragma unroll
                for (int rj = 0; rj < 4; ++rj) {
                    int row = (rg3*4 + rj)*16 + ln;
                    half8 bf = *(const half8*)(hS + row*HSTR + kst*32 + q*8);
                    z[rj] = MFMA(wO, bf, z[rj]);
                }
            }
            // rows encode (j = rg3*2 + (rj>>1), b = (rj&1)*16 + ln); clamped
            // rows now genuinely duplicate (s=127, same b) -> merge all
            #pragma unroll
            for (int i = 0; i < 4; ++i) {
                rz0[i] = fmaxf(rz0[i], fmaxf(z[0][i], z[2][i]));
                rz1[i] = fmaxf(rz1[i], fmaxf(z[1][i], z[3][i]));
            }
        }
        __syncthreads();                             // protect hS/cmx for next item
    }

    if (cur_t >= 0) {
        #pragma unroll
        for (int i = 0; i < 4; ++i) {
            float yA = 1.f / (1.f + __expf(-5.f * rz0[i]));
            float yB = 1.f / (1.f + __expf(-5.f * rz1[i]));
            int o = og*16 + q*4 + i;
            atomicMax(&outU[(size_t)ln*(TT*OO) + cur_t*OO + o], __float_as_uint(yA));
            atomicMax(&outU[(size_t)(16+ln)*(TT*OO) + cur_t*OO + o], __float_as_uint(yB));
        }
    }
}

extern "C" void kernel_launch(void* const* d_in, const int* in_sizes, int n_in,
                              void* d_out, int out_size, void* d_ws, size_t ws_size,
                              hipStream_t stream) {
    const float* P  = (const float*)d_in[0];
    const float* W1 = (const float*)d_in[1];
    const float* b1 = (const float*)d_in[2];
    const float* W2 = (const float*)d_in[3];
    const float* b2 = (const float*)d_in[4];
    const float* W3 = (const float*)d_in[5];
    const float* b3 = (const float*)d_in[6];

    tll_prep_wt<<<272, 256, 0, stream>>>(P, W1, b1, W2, b2, W3, (char*)d_ws);
    tll_prep_pw<<<64, 256, 0, stream>>>(P, (char*)d_ws);
    hipMemsetAsync(d_out, 0, (size_t)out_size * sizeof(float), stream);

    hipFuncSetAttribute((const void*)tll_main,
                        hipFuncAttributeMaxDynamicSharedMemorySize, 75776);
    tll_main<<<256, 512, 75776, stream>>>(P, b3, (const char*)d_ws,
                                          (unsigned int*)d_out);
}

// Round 6
// 370.490 us; speedup vs baseline: 1.0057x; 1.0057x over previous
//
#include <hip/hip_runtime.h>

// TemporalLogicLayer R6: R5 + register CARRY of the running max across items.
// out[b,t,o] = max_{s>=t} sigmoid(5*(relu(relu([cummax(P[t..s])|P[s]]W1+b1)W2+b2)W3+b3))
//
// R5 regression root-cause: per-item TAB reads (5.2 MB table, 64 KB/item,
// scattered) thrashed the 4 MB/XCD L2, evicting the weights that are re-read
// from global every item -> 307 MB HBM FETCH. R6: blocks own contiguous
// t-major ranges and chunks of one t arrive c-ascending, so the staging
// threads carry mi (cummax of P[b, t..s0-1, d]) in registers across items.
// TAB is read only when a block's range starts mid-t (once per block).
// Hot set = W + PW ~ 1.5 MB -> L2-resident; weight re-reads become L2 hits.
//
// Structure (from R4/R5):
// - per-(b,o) max in registers in the z-domain (sigmoid monotone), flushed by
//   atomicMax on t-change only.
// - W1/W2/W3 A-operand fragments read from L2-resident global ws.
// - LDS = hS(43008) + cmx(32768) = 75776 B -> 2 blocks/CU, 4 waves/SIMD.
// - preps: merged weights+sparse-table kernel (272 blocks), PW builder (64).

#define TT 128
#define BB 32
#define DD 128
#define OO 64
#define NP 144
#define HSTR 168
#define N_ITEMS 2112

typedef __attribute__((ext_vector_type(8))) _Float16 half8;
typedef __attribute__((ext_vector_type(4))) _Float16 half4;
typedef __attribute__((ext_vector_type(4))) float f32x4;

// ws layout (bytes)
#define W1T_OFF 0                                   // f16 [144][256]
#define W2T_OFF (W1T_OFF + 144*256*2)               // f16 [144][160]
#define W3T_OFF (W2T_OFF + 144*160*2)               // f16 [64][160]
#define B1P_OFF (W3T_OFF + 64*160*2)                // f32 [144]
#define B2P_OFF (B1P_OFF + 144*4)                   // f32 [144]
#define PW_OFF  (B2P_OFF + 144*4)                   // f16 [4096][144]
#define TAB_OFF (PW_OFF + 4096*144*2)               // f16 [5][128][32][128]

#define MFMA(A, B, C) __builtin_amdgcn_mfma_f32_16x16x32_f16((A), (B), (C), 0, 0, 0)

__device__ __forceinline__ half8 h8max(half8 a, half8 b) {
    half8 r;
    #pragma unroll
    for (int i = 0; i < 8; ++i) r[i] = (a[i] > b[i]) ? a[i] : b[i];
    return r;
}

// ---------- prep A (272 blocks): weights transpose + sparse max table ----------
__global__ void tll_prep_wt(const float* __restrict__ P,
                            const float* __restrict__ W1, const float* __restrict__ b1,
                            const float* __restrict__ W2, const float* __restrict__ b2,
                            const float* __restrict__ W3, char* __restrict__ ws) {
    __shared__ _Float16 tb[2][128 * 32];            // 16 KB (tab part only)
    const int blk = blockIdx.x, tid = threadIdx.x;
    if (blk < 144) {
        _Float16* W1t = (_Float16*)(ws + W1T_OFF);
        _Float16* W2t = (_Float16*)(ws + W2T_OFF);
        _Float16* W3t = (_Float16*)(ws + W3T_OFF);
        float*    b1p = (float*)(ws + B1P_OFF);
        float*    b2p = (float*)(ws + B2P_OFF);
        int idx = blk * 256 + tid;
        if (idx < 144*256) {                        // W1t[n][k] = W1[k][n]
            int n = idx >> 8, k = idx & 255;
            W1t[idx] = (_Float16)((n < 132) ? W1[k*132 + n] : 0.f);
        }
        if (idx < 144*160) {                        // W2t[n][k] = W2[k][n]
            int n = idx / 160, k = idx - n*160;
            W2t[idx] = (_Float16)((n < 132 && k < 132) ? W2[k*132 + n] : 0.f);
        }
        if (idx < 64*160) {                         // W3t[o][k] = W3[k][o]
            int o = idx / 160, k = idx - o*160;
            W3t[idx] = (_Float16)((k < 132) ? W3[k*64 + o] : 0.f);
        }
        if (idx < 144) {
            b1p[idx] = (idx < 132) ? b1[idx] : 0.f;
            b2p[idx] = (idx < 132) ? b2[idx] : 0.f;
        }
    } else {
        const int bb = blk - 144;                   // 128 blocks: (b, d-quarter)
        const int b = bb >> 2, d0 = (bb & 3) * 32;
        _Float16* TAB = (_Float16*)(ws + TAB_OFF);
        for (int i = tid; i < 4096; i += 256)
            tb[0][i] = (_Float16)P[b*(TT*DD) + (i >> 5)*DD + d0 + (i & 31)];
        __syncthreads();
        for (int i = tid; i < 4096; i += 256) {     // level 0: window 4
            int t = i >> 5, di = i & 31;
            _Float16 v = tb[0][i];
            #pragma unroll
            for (int dt = 1; dt < 4; ++dt) {
                int s = t + dt; if (s > 127) s = 127;
                _Float16 u = tb[0][s*32 + di];
                v = (u > v) ? u : v;
            }
            tb[1][i] = v;
            TAB[t*4096 + b*128 + d0 + di] = v;
        }
        __syncthreads();
        int src = 1;
        for (int lev = 1; lev < 5; ++lev) {         // windows 8,16,32,64
            int shift = 1 << (lev + 1);
            for (int i = tid; i < 4096; i += 256) {
                int t = i >> 5, di = i & 31;
                int s = t + shift; if (s > 127) s = 127;
                _Float16 a = tb[src][i], c = tb[src][s*32 + di];
                _Float16 v = (c > a) ? c : a;
                tb[src ^ 1][i] = v;
                TAB[(size_t)lev*524288 + t*4096 + b*128 + d0 + di] = v;
            }
            __syncthreads();
            src ^= 1;
        }
    }
}

// ---------- prep B (64 blocks): PW[row][n] = P[row] @ W1[128:256,:] ----------
__global__ void tll_prep_pw(const float* __restrict__ P, char* __restrict__ ws) {
    const _Float16* W1t = (const _Float16*)(ws + W1T_OFF);
    _Float16* PW = (_Float16*)(ws + PW_OFF);
    const int tid = threadIdx.x, w = tid >> 6, lane = tid & 63;
    const int ln = lane & 15, q = lane >> 4;
    const int row = (blockIdx.x*4 + w)*16 + ln;     // 0..4095
    const int b_ = row & 31, s_ = row >> 5;
    const float* pp = P + b_*(TT*DD) + s_*DD;
    half8 Bf[4];
    #pragma unroll
    for (int kst = 0; kst < 4; ++kst) {
        f32x4 p0 = *(const f32x4*)(pp + kst*32 + q*8);
        f32x4 p1 = *(const f32x4*)(pp + kst*32 + q*8 + 4);
        half8 h;
        #pragma unroll
        for (int i = 0; i < 4; ++i) { h[i] = (_Float16)p0[i]; h[4+i] = (_Float16)p1[i]; }
        Bf[kst] = h;
    }
    for (int mt = 0; mt < 9; ++mt) {
        f32x4 acc = (f32x4){0.f, 0.f, 0.f, 0.f};
        #pragma unroll
        for (int kst = 0; kst < 4; ++kst) {
            half8 A = *(const half8*)(W1t + (mt*16 + ln)*256 + 128 + kst*32 + q*8);
            acc = MFMA(A, Bf[kst], acc);
        }
        half4 hv;
        #pragma unroll
        for (int i = 0; i < 4; ++i) hv[i] = (_Float16)acc[i];
        *(half4*)(PW + (size_t)row*NP + mt*16 + q*4) = hv;
    }
}

// ---------- main ----------
__global__ __launch_bounds__(512, 4) void tll_main(
    const float* __restrict__ P, const float* __restrict__ b3,
    const char* __restrict__ ws, unsigned int* __restrict__ outU)
{
    extern __shared__ char smem[];
    _Float16* hS  = (_Float16*)smem;                // [128][168] = 43008 B
    _Float16* cmx = hS + 128*HSTR;                  // [128][128] swizzled, 32768 B

    const _Float16* W1t = (const _Float16*)(ws + W1T_OFF);
    const _Float16* W2t = (const _Float16*)(ws + W2T_OFF);
    const _Float16* W3t = (const _Float16*)(ws + W3T_OFF);
    const float*    b1p = (const float*)(ws + B1P_OFF);
    const float*    b2p = (const float*)(ws + B2P_OFF);
    const _Float16* PW  = (const _Float16*)(ws + PW_OFF);
    const _Float16* TAB = (const _Float16*)(ws + TAB_OFF);

    const int tid = threadIdx.x, w = tid >> 6, lane = tid & 63;
    const int ln = lane & 15, q = lane >> 4;
    const int fg = w >> 1, rg = w & 1;              // 4 f-groups x 2 r-groups
    const bool has3 = (fg == 0);                    // f-tiles (3,2,2,2) of 9
    const int fb = (fg == 0) ? 0 : (16 + 32*fg);    // 0,48,80,112
    const int f0A = fb, f0B = fb + 16, f0C = fb + 32;
    const int og = fg, rg3 = rg;                    // L3: o-tile, j-group

    // zero hS cols 144..159 (K=144..159 read by L2'/L3'; paired W rows are 0,
    // but LDS garbage could be NaN -> keep a real zero strip)
    for (int idx = tid; idx < 256; idx += 512) {
        int row = idx >> 1, hv = idx & 1;
        half8 z;
        #pragma unroll
        for (int i = 0; i < 8; ++i) z[i] = (_Float16)0.f;
        *(half8*)(hS + row*HSTR + 144 + hv*8) = z;
    }

    const int sb = tid >> 4, dblk = tid & 15, d0 = dblk*8;  // staging role

    const int bid = blockIdx.x;
    int it = (bid*33) >> 2;                          // contiguous t-major ranges
    const int hi = ((bid + 1)*33) >> 2;

    int cur_t = -1;
    f32x4 rz0 = (f32x4){-1e30f,-1e30f,-1e30f,-1e30f};  // z-domain max, b=ln
    f32x4 rz1 = rz0;                                    // b=16+ln
    half8 mi;                                           // carried cummax P[b,t..s0-1,d]
    __syncthreads();

    for (; it < hi; ++it) {
        // ---- decode item -> (t, c) ----
        int g = (int)((65.0f - sqrtf((float)(4225 - 2*it))) * 0.5f);
        if (g < 0) g = 0; if (g > 31) g = 31;
        while (g > 0 && 2*g*(65 - g) > it) --g;
        while (2*(g+1)*(65 - (g+1)) <= it) ++g;
        int rem = it - 2*g*(65 - g);
        int ntc = 32 - g;
        int t  = 4*g + rem/ntc;
        int c  = rem - (rem/ntc)*ntc;
        int s0 = t + 4*c;

        // ---- t-change: flush z-max, reset carry ----
        if (t != cur_t) {
            if (cur_t >= 0) {
                #pragma unroll
                for (int i = 0; i < 4; ++i) {
                    float yA = 1.f / (1.f + __expf(-5.f * rz0[i]));
                    float yB = 1.f / (1.f + __expf(-5.f * rz1[i]));
                    int o = og*16 + q*4 + i;
                    atomicMax(&outU[(size_t)ln*(TT*OO) + cur_t*OO + o], __float_as_uint(yA));
                    atomicMax(&outU[(size_t)(16+ln)*(TT*OO) + cur_t*OO + o], __float_as_uint(yB));
                }
            }
            cur_t = t;
            rz0 = (f32x4){-1e30f,-1e30f,-1e30f,-1e30f};
            rz1 = rz0;
            // init carry: c==0 -> -inf; c>0 only possible on a block's FIRST
            // item (ranges are t-major contiguous) -> one TAB lookup per block
            if (c == 0) {
                #pragma unroll
                for (int i = 0; i < 8; ++i) mi[i] = (_Float16)(-65504.0f);
            } else {
                int L = 4*c;
                int klev = 31 - __builtin_clz(L);
                int t2 = s0 - (1 << klev);
                const _Float16* tb = TAB + (size_t)(klev - 2)*524288;
                half8 x = *(const half8*)(tb + t*4096 + sb*128 + d0);
                half8 y = *(const half8*)(tb + t2*4096 + sb*128 + d0);
                mi = h8max(x, y);
            }
        }

        // ---- stage cmx: fold 4 steps onto carried mi ----
        {
            const float* pb = P + sb*(TT*DD) + d0;
            #pragma unroll
            for (int j = 0; j < 4; ++j) {
                int s = s0 + j; if (s > 127) s = 127;   // clamp: same b, s=127 dup;
                f32x4 p0 = *(const f32x4*)(pb + s*DD);  // only in a t's LAST chunk,
                f32x4 p1 = *(const f32x4*)(pb + s*DD + 4); // never carried onward
                half8 ph;
                #pragma unroll
                for (int i = 0; i < 4; ++i) { ph[i] = (_Float16)p0[i]; ph[4+i] = (_Float16)p1[i]; }
                mi = h8max(mi, ph);
                int row = j*32 + sb;
                *(half8*)(cmx + row*128 + ((dblk ^ (row & 15))*8)) = mi;
            }
        }
        __syncthreads();                             // [A]

        // ---- L1': z1^T = W1a^T @ cmx^T, init = PW + b1, relu -> hS ----
        {
            const f32x4 bA1 = *(const f32x4*)(b1p + f0A + q*4);
            const f32x4 bB1 = *(const f32x4*)(b1p + f0B + q*4);
            f32x4 aA[4], aB[4], aC[4];
            #pragma unroll
            for (int rj = 0; rj < 4; ++rj) {
                int row = (rg*4 + rj)*16 + ln;           // M-row: j = row>>5, b = row&31
                int sj = s0 + (row >> 5);                // clamp s ONLY, preserve b
                if (sj > 127) sj = 127;
                int rowg = sj*32 + (row & 31);
                const _Float16* pwp = PW + (size_t)rowg*NP;
                half4 pA = *(const half4*)(pwp + f0A + q*4);
                half4 pB = *(const half4*)(pwp + f0B + q*4);
                aA[rj] = bA1; aB[rj] = bB1;
                #pragma unroll
                for (int i = 0; i < 4; ++i) { aA[rj][i] += (float)pA[i]; aB[rj][i] += (float)pB[i]; }
                if (has3) {
                    const f32x4 bC1 = *(const f32x4*)(b1p + f0C + q*4);
                    half4 pC = *(const half4*)(pwp + f0C + q*4);
                    aC[rj] = bC1;
                    #pragma unroll
                    for (int i = 0; i < 4; ++i) aC[rj][i] += (float)pC[i];
                }
            }
            #pragma unroll
            for (int kst = 0; kst < 4; ++kst) {
                half8 wA = *(const half8*)(W1t + (f0A+ln)*256 + kst*32 + q*8);
                half8 wB = *(const half8*)(W1t + (f0B+ln)*256 + kst*32 + q*8);
                half8 wC;
                if (has3) wC = *(const half8*)(W1t + (f0C+ln)*256 + kst*32 + q*8);
                int kb = kst*4 + q;
                #pragma unroll
                for (int rj = 0; rj < 4; ++rj) {
                    int row = (rg*4 + rj)*16 + ln;
                    half8 bf = *(const half8*)(cmx + row*128 + ((kb ^ (row & 15))*8));
                    aA[rj] = MFMA(wA, bf, aA[rj]);
                    aB[rj] = MFMA(wB, bf, aB[rj]);
                    if (has3) aC[rj] = MFMA(wC, bf, aC[rj]);
                }
            }
            #pragma unroll
            for (int rj = 0; rj < 4; ++rj) {
                int row = (rg*4 + rj)*16 + ln;
                half4 hA, hB, hC;
                #pragma unroll
                for (int i = 0; i < 4; ++i) {
                    hA[i] = (_Float16)fmaxf(aA[rj][i], 0.f);
                    hB[i] = (_Float16)fmaxf(aB[rj][i], 0.f);
                }
                *(half4*)(hS + row*HSTR + f0A + q*4) = hA;
                *(half4*)(hS + row*HSTR + f0B + q*4) = hB;
                if (has3) {
                    #pragma unroll
                    for (int i = 0; i < 4; ++i) hC[i] = (_Float16)fmaxf(aC[rj][i], 0.f);
                    *(half4*)(hS + row*HSTR + f0C + q*4) = hC;
                }
            }
        }
        __syncthreads();                             // [B]

        // ---- L2': z2^T = W2^T @ h1^T, relu (held in regs until [C]) ----
        half4 h2A[4], h2B[4], h2C[4];
        {
            const f32x4 bA2 = *(const f32x4*)(b2p + f0A + q*4);
            const f32x4 bB2 = *(const f32x4*)(b2p + f0B + q*4);
            f32x4 aA[4], aB[4], aC[4];
            #pragma unroll
            for (int rj = 0; rj < 4; ++rj) {
                aA[rj] = bA2; aB[rj] = bB2;
                if (has3) aC[rj] = *(const f32x4*)(b2p + f0C + q*4);
            }
            #pragma unroll
            for (int kst = 0; kst < 5; ++kst) {
                half8 wA = *(const half8*)(W2t + (f0A+ln)*160 + kst*32 + q*8);
                half8 wB = *(const half8*)(W2t + (f0B+ln)*160 + kst*32 + q*8);
                half8 wC;
                if (has3) wC = *(const half8*)(W2t + (f0C+ln)*160 + kst*32 + q*8);
                #pragma unroll
                for (int rj = 0; rj < 4; ++rj) {
                    int row = (rg*4 + rj)*16 + ln;
                    half8 bf = *(const half8*)(hS + row*HSTR + kst*32 + q*8);
                    aA[rj] = MFMA(wA, bf, aA[rj]);
                    aB[rj] = MFMA(wB, bf, aB[rj]);
                    if (has3) aC[rj] = MFMA(wC, bf, aC[rj]);
                }
            }
            #pragma unroll
            for (int rj = 0; rj < 4; ++rj) {
                #pragma unroll
                for (int i = 0; i < 4; ++i) {
                    h2A[rj][i] = (_Float16)fmaxf(aA[rj][i], 0.f);
                    h2B[rj][i] = (_Float16)fmaxf(aB[rj][i], 0.f);
                    if (has3) h2C[rj][i] = (_Float16)fmaxf(aC[rj][i], 0.f);
                }
            }
        }
        __syncthreads();                             // [C] all h1 reads done
        #pragma unroll
        for (int rj = 0; rj < 4; ++rj) {
            int row = (rg*4 + rj)*16 + ln;
            *(half4*)(hS + row*HSTR + f0A + q*4) = h2A[rj];
            *(half4*)(hS + row*HSTR + f0B + q*4) = h2B[rj];
            if (has3) *(half4*)(hS + row*HSTR + f0C + q*4) = h2C[rj];
        }
        __syncthreads();                             // [D]

        // ---- L3': z3^T = W3^T @ h2^T; merge into register z-max ----
        {
            const f32x4 bz3 = *(const f32x4*)(b3 + og*16 + q*4);
            f32x4 z[4];
            #pragma unroll
            for (int rj = 0; rj < 4; ++rj) z[rj] = bz3;
            #pragma unroll
            for (int kst = 0; kst < 5; ++kst) {
                half8 wO = *(const half8*)(W3t + (og*16+ln)*160 + kst*32 + q*8);
                #pragma unroll
                for (int rj = 0; rj < 4; ++rj) {
                    int row = (rg3*4 + rj)*16 + ln;
                    half8 bf = *(const half8*)(hS + row*HSTR + kst*32 + q*8);
                    z[rj] = MFMA(wO, bf, z[rj]);
                }
            }
            // rows encode (j = rg3*2 + (rj>>1), b = (rj&1)*16 + ln); clamped
            // rows duplicate (s=127, same b) -> merge all unconditionally
            #pragma unroll
            for (int i = 0; i < 4; ++i) {
                rz0[i] = fmaxf(rz0[i], fmaxf(z[0][i], z[2][i]));
                rz1[i] = fmaxf(rz1[i], fmaxf(z[1][i], z[3][i]));
            }
        }
        __syncthreads();                             // protect hS/cmx for next item
    }

    if (cur_t >= 0) {
        #pragma unroll
        for (int i = 0; i < 4; ++i) {
            float yA = 1.f / (1.f + __expf(-5.f * rz0[i]));
            float yB = 1.f / (1.f + __expf(-5.f * rz1[i]));
            int o = og*16 + q*4 + i;
            atomicMax(&outU[(size_t)ln*(TT*OO) + cur_t*OO + o], __float_as_uint(yA));
            atomicMax(&outU[(size_t)(16+ln)*(TT*OO) + cur_t*OO + o], __float_as_uint(yB));
        }
    }
}

extern "C" void kernel_launch(void* const* d_in, const int* in_sizes, int n_in,
                              void* d_out, int out_size, void* d_ws, size_t ws_size,
                              hipStream_t stream) {
    const float* P  = (const float*)d_in[0];
    const float* W1 = (const float*)d_in[1];
    const float* b1 = (const float*)d_in[2];
    const float* W2 = (const float*)d_in[3];
    const float* b2 = (const float*)d_in[4];
    const float* W3 = (const float*)d_in[5];
    const float* b3 = (const float*)d_in[6];

    tll_prep_wt<<<272, 256, 0, stream>>>(P, W1, b1, W2, b2, W3, (char*)d_ws);
    tll_prep_pw<<<64, 256, 0, stream>>>(P, (char*)d_ws);
    hipMemsetAsync(d_out, 0, (size_t)out_size * sizeof(float), stream);

    hipFuncSetAttribute((const void*)tll_main,
                        hipFuncAttributeMaxDynamicSharedMemorySize, 75776);
    tll_main<<<256, 512, 75776, stream>>>(P, b3, (const char*)d_ws,
                                          (unsigned int*)d_out);
}

// Round 7
// 234.845 us; speedup vs baseline: 1.5866x; 1.5776x over previous
//
#include <hip/hip_runtime.h>

// TemporalLogicLayer R7: no atomics (slot flush + finalize), L2-resident hot set.
// out[b,t,o] = max_{s>=t} sigmoid(5*(relu(relu([cummax(P[t..s])|P[s]]W1+b1)W2+b2)W3+b3))
//
// R6 post-mortem: 293 MB FETCH was ~97 MB atomic line-reads (1.5M device-scope
// atomicMax; WRITE_SIZE 92 MB = the matching write side) + weight/PW re-reads
// missing a 4.3 MB/XCD working set (W+PW+P+TAB marginally > 4 MB L2).
// R7 changes:
// - flush-on-t-change now writes z-max to ws slots [t][k][b][o] (k = bid -
//   bid_first(t), k<5 under contiguous t-major ranges) with nontemporal f32x4
//   stores; rg3-pair merge via scratch in cmx (dead at flush). finalize kernel
//   maxes slots, applies sigmoid(5z), writes out. Zero global atomics.
// - TAB dropped; block-start mid-t carry init = direct scan of Pf rows [t,s0)
//   (once per block). P pre-converted to f16 Pf (1 MB). W1t stored K<128 only.
//   Hot set = W(0.10) + PW(1.18) + Pf(1.05) ~ 2.3 MB -> L2-resident.
// - single prep kernel, 240 blocks: [0,144) W-transpose+biases, [144,208) PW
//   (reads f32 W1 directly), [208,240) Pf convert. PW: M=rows of (s,b), one
//   GEMM vs W1[128:,:] (the t-invariant half of L1).

#define TT 128
#define BB 32
#define DD 128
#define OO 64
#define NP 144
#define HSTR 168
#define KSLOT 5

typedef __attribute__((ext_vector_type(8))) _Float16 half8;
typedef __attribute__((ext_vector_type(4))) _Float16 half4;
typedef __attribute__((ext_vector_type(4))) float f32x4;

// ws layout (bytes)
#define W1T_OFF 0                                   // f16 [144][128] (K<128 half)
#define W2T_OFF (W1T_OFF + 144*128*2)               // f16 [144][160]
#define W3T_OFF (W2T_OFF + 144*160*2)               // f16 [64][160]
#define B1P_OFF (W3T_OFF + 64*160*2)                // f32 [144]
#define B2P_OFF (B1P_OFF + 144*4)                   // f32 [144]
#define PW_OFF  (B2P_OFF + 144*4)                   // f16 [4096][144]
#define PF_OFF  (PW_OFF + 4096*144*2)               // f16 [32][128][128]
#define SLOT_OFF (PF_OFF + 32*128*128*2)            // f32 [128][KSLOT][32][64]

#define MFMA(A, B, C) __builtin_amdgcn_mfma_f32_16x16x32_f16((A), (B), (C), 0, 0, 0)

__device__ __forceinline__ half8 h8max(half8 a, half8 b) {
    half8 r;
    #pragma unroll
    for (int i = 0; i < 8; ++i) r[i] = (a[i] > b[i]) ? a[i] : b[i];
    return r;
}

// largest bid with range_start(bid) = (bid*33)>>2 <= it
__device__ __forceinline__ int bid_of(int it) {
    int bb = (4 * it) / 33;
    while ((((bb + 1) * 33) >> 2) <= it) ++bb;
    while (((bb * 33) >> 2) > it) --bb;
    return bb;
}

// ---------- prep (240 blocks x 256) ----------
__global__ void tll_prep(const float* __restrict__ P,
                         const float* __restrict__ W1, const float* __restrict__ b1,
                         const float* __restrict__ W2, const float* __restrict__ b2,
                         const float* __restrict__ W3, char* __restrict__ ws) {
    const int blk = blockIdx.x, tid = threadIdx.x;
    if (blk < 144) {
        _Float16* W1t = (_Float16*)(ws + W1T_OFF);
        _Float16* W2t = (_Float16*)(ws + W2T_OFF);
        _Float16* W3t = (_Float16*)(ws + W3T_OFF);
        float*    b1p = (float*)(ws + B1P_OFF);
        float*    b2p = (float*)(ws + B2P_OFF);
        int idx = blk * 256 + tid;
        if (idx < 144*128) {                        // W1t[n][k] = W1[k][n], k<128
            int n = idx >> 7, k = idx & 127;
            W1t[idx] = (_Float16)((n < 132) ? W1[k*132 + n] : 0.f);
        }
        if (idx < 144*160) {                        // W2t[n][k] = W2[k][n]
            int n = idx / 160, k = idx - n*160;
            W2t[idx] = (_Float16)((n < 132 && k < 132) ? W2[k*132 + n] : 0.f);
        }
        if (idx < 64*160) {                         // W3t[o][k] = W3[k][o]
            int o = idx / 160, k = idx - o*160;
            W3t[idx] = (_Float16)((k < 132) ? W3[k*64 + o] : 0.f);
        }
        if (idx < 144) {
            b1p[idx] = (idx < 132) ? b1[idx] : 0.f;
            b2p[idx] = (idx < 132) ? b2[idx] : 0.f;
        }
    } else if (blk < 208) {
        // PW[row][n] = P[row] @ W1[128:256, :], row = s*32+b
        _Float16* PW = (_Float16*)(ws + PW_OFF);
        const int blkp = blk - 144;
        const int w = tid >> 6, lane = tid & 63;
        const int ln = lane & 15, q = lane >> 4;
        const int row = (blkp*4 + w)*16 + ln;       // 0..4095
        const int b_ = row & 31, s_ = row >> 5;
        const float* pp = P + b_*(TT*DD) + s_*DD;
        half8 Bf[4];
        #pragma unroll
        for (int kst = 0; kst < 4; ++kst) {
            f32x4 p0 = *(const f32x4*)(pp + kst*32 + q*8);
            f32x4 p1 = *(const f32x4*)(pp + kst*32 + q*8 + 4);
            half8 h;
            #pragma unroll
            for (int i = 0; i < 4; ++i) { h[i] = (_Float16)p0[i]; h[4+i] = (_Float16)p1[i]; }
            Bf[kst] = h;
        }
        for (int mt = 0; mt < 9; ++mt) {
            f32x4 acc = (f32x4){0.f, 0.f, 0.f, 0.f};
            #pragma unroll
            for (int kst = 0; kst < 4; ++kst) {
                half8 A;                            // W1 rows 128+kst*32+q*8+i, col mt*16+ln
                const float* wp = W1 + (size_t)(128 + kst*32 + q*8)*132 + mt*16 + ln;
                #pragma unroll
                for (int i = 0; i < 8; ++i) A[i] = (_Float16)wp[i*132];
                acc = MFMA(A, Bf[kst], acc);
            }
            half4 hv;
            #pragma unroll
            for (int i = 0; i < 4; ++i) hv[i] = (_Float16)acc[i];
            *(half4*)(PW + (size_t)row*NP + mt*16 + q*4) = hv;
        }
    } else {
        // Pf[b] = f16(P[b])
        _Float16* Pf = (_Float16*)(ws + PF_OFF);
        const int b = blk - 208;
        const f32x4* src = (const f32x4*)(P + (size_t)b * TT * DD);
        half4* dst = (half4*)(Pf + (size_t)b * TT * DD);
        for (int i = tid; i < TT*DD/4; i += 256) {
            f32x4 v = src[i];
            half4 h;
            #pragma unroll
            for (int j = 0; j < 4; ++j) h[j] = (_Float16)v[j];
            dst[i] = h;
        }
    }
}

// ---------- finalize (128 blocks x 512): out = sigmoid(5 * max_k slots) ----------
__global__ void tll_finalize(const char* __restrict__ ws, float* __restrict__ out) {
    const int t = blockIdx.x, tid = threadIdx.x;
    const int g = t >> 2;
    const int it_s = 2*g*(65 - g) + (t - 4*g)*(32 - g);
    const int it_e = it_s + (32 - g);
    const int n = bid_of(it_e - 1) - bid_of(it_s) + 1;     // <= KSLOT
    const float* slots = (const float*)(ws + SLOT_OFF) + (size_t)t * KSLOT * 2048;
    const int cell = tid * 4;                              // 2048 cells: b*64+o
    f32x4 v = *(const f32x4*)(slots + cell);
    for (int k = 1; k < n; ++k) {
        f32x4 u = *(const f32x4*)(slots + k*2048 + cell);
        #pragma unroll
        for (int i = 0; i < 4; ++i) v[i] = fmaxf(v[i], u[i]);
    }
    f32x4 y;
    #pragma unroll
    for (int i = 0; i < 4; ++i) y[i] = 1.f / (1.f + __expf(-5.f * v[i]));
    const int b = cell >> 6, o = cell & 63;
    *(f32x4*)(out + (size_t)b*(TT*OO) + t*OO + o) = y;
}

// ---------- main ----------
__global__ __launch_bounds__(512, 4) void tll_main(
    const float* __restrict__ b3, char* __restrict__ ws)
{
    extern __shared__ char smem[];
    _Float16* hS  = (_Float16*)smem;                // [128][168] = 43008 B
    _Float16* cmx = hS + 128*HSTR;                  // [128][128] swizzled, 32768 B

    const _Float16* W1t = (const _Float16*)(ws + W1T_OFF);
    const _Float16* W2t = (const _Float16*)(ws + W2T_OFF);
    const _Float16* W3t = (const _Float16*)(ws + W3T_OFF);
    const float*    b1p = (const float*)(ws + B1P_OFF);
    const float*    b2p = (const float*)(ws + B2P_OFF);
    const _Float16* PW  = (const _Float16*)(ws + PW_OFF);
    const _Float16* Pf  = (const _Float16*)(ws + PF_OFF);
    float*          slots = (float*)(ws + SLOT_OFF);

    const int tid = threadIdx.x, w = tid >> 6, lane = tid & 63;
    const int ln = lane & 15, q = lane >> 4;
    const int fg = w >> 1, rg = w & 1;              // 4 f-groups x 2 r-groups
    const bool has3 = (fg == 0);                    // f-tiles (3,2,2,2) of 9
    const int fb = (fg == 0) ? 0 : (16 + 32*fg);    // 0,48,80,112
    const int f0A = fb, f0B = fb + 16, f0C = fb + 32;
    const int og = fg, rg3 = rg;                    // L3: o-tile, j-group

    // zero hS cols 144..159 (K padding read by L2'/L3'; avoid NaN garbage)
    for (int idx = tid; idx < 256; idx += 512) {
        int row = idx >> 1, hv = idx & 1;
        half8 z;
        #pragma unroll
        for (int i = 0; i < 8; ++i) z[i] = (_Float16)0.f;
        *(half8*)(hS + row*HSTR + 144 + hv*8) = z;
    }

    const int sb = tid >> 4, dblk = tid & 15, d0 = dblk*8;  // staging role
    const _Float16* pfb = Pf + (size_t)sb*(TT*DD) + d0;

    const int bid = blockIdx.x;
    int it = (bid*33) >> 2;                          // contiguous t-major ranges
    const int hi = ((bid + 1)*33) >> 2;

    int cur_t = -1;
    f32x4 rz0 = (f32x4){-1e30f,-1e30f,-1e30f,-1e30f};  // z-domain max, b=ln
    f32x4 rz1 = rz0;                                    // b=16+ln
    half8 mi;                                           // carried cummax Pf[b,t..s0-1,d]
    __syncthreads();

    for (; it < hi; ++it) {
        // ---- decode item -> (t, c) ----
        int g = (int)((65.0f - sqrtf((float)(4225 - 2*it))) * 0.5f);
        if (g < 0) g = 0; if (g > 31) g = 31;
        while (g > 0 && 2*g*(65 - g) > it) --g;
        while (2*(g+1)*(65 - (g+1)) <= it) ++g;
        int rem = it - 2*g*(65 - g);
        int ntc = 32 - g;
        int t  = 4*g + rem/ntc;
        int c  = rem - (rem/ntc)*ntc;
        int s0 = t + 4*c;

        // ---- t-change: flush z-max to slot, reset + scan-init carry ----
        if (t != cur_t) {                            // block-uniform branch
            if (cur_t >= 0) {
                float* scr = (float*)cmx;            // cmx is dead here
                if (rg3 == 1) {
                    *(f32x4*)(scr + (og*64 + lane)*8)     = rz0;
                    *(f32x4*)(scr + (og*64 + lane)*8 + 4) = rz1;
                }
                __syncthreads();
                if (rg3 == 0) {
                    f32x4 p0 = *(const f32x4*)(scr + (og*64 + lane)*8);
                    f32x4 p1 = *(const f32x4*)(scr + (og*64 + lane)*8 + 4);
                    #pragma unroll
                    for (int i = 0; i < 4; ++i) {
                        rz0[i] = fmaxf(rz0[i], p0[i]);
                        rz1[i] = fmaxf(rz1[i], p1[i]);
                    }
                    int k = bid - bid_of(2*(cur_t >> 2)*(65 - (cur_t >> 2))
                                         + (cur_t - 4*(cur_t >> 2))*(32 - (cur_t >> 2)));
                    float* sp = slots + ((size_t)cur_t*KSLOT + k)*2048;
                    int o = og*16 + q*4;
                    __builtin_nontemporal_store(rz0, (f32x4*)(sp + ln*64 + o));
                    __builtin_nontemporal_store(rz1, (f32x4*)(sp + (16+ln)*64 + o));
                }
                __syncthreads();                     // protect scr before staging
            }
            cur_t = t;
            rz0 = (f32x4){-1e30f,-1e30f,-1e30f,-1e30f};
            rz1 = rz0;
            #pragma unroll
            for (int i = 0; i < 8; ++i) mi[i] = (_Float16)(-65504.0f);
            for (int s = t; s < s0; ++s)             // nonempty only at block start
                mi = h8max(mi, *(const half8*)(pfb + s*DD));
        }

        // ---- stage cmx: fold 4 steps onto carried mi ----
        #pragma unroll
        for (int j = 0; j < 4; ++j) {
            int s = s0 + j; if (s > 127) s = 127;    // dup of valid s=127, same b;
            mi = h8max(mi, *(const half8*)(pfb + s*DD)); // only in t's last chunk
            int row = j*32 + sb;
            *(half8*)(cmx + row*128 + ((dblk ^ (row & 15))*8)) = mi;
        }
        __syncthreads();                             // [A]

        // ---- L1': z1^T = W1a^T @ cmx^T, init = PW + b1, relu -> hS ----
        {
            const f32x4 bA1 = *(const f32x4*)(b1p + f0A + q*4);
            const f32x4 bB1 = *(const f32x4*)(b1p + f0B + q*4);
            f32x4 aA[4], aB[4], aC[4];
            #pragma unroll
            for (int rj = 0; rj < 4; ++rj) {
                int row = (rg*4 + rj)*16 + ln;           // j = row>>5, b = row&31
                int sj = s0 + (row >> 5);                // clamp s ONLY, preserve b
                if (sj > 127) sj = 127;
                int rowg = sj*32 + (row & 31);
                const _Float16* pwp = PW + (size_t)rowg*NP;
                half4 pA = *(const half4*)(pwp + f0A + q*4);
                half4 pB = *(const half4*)(pwp + f0B + q*4);
                aA[rj] = bA1; aB[rj] = bB1;
                #pragma unroll
                for (int i = 0; i < 4; ++i) { aA[rj][i] += (float)pA[i]; aB[rj][i] += (float)pB[i]; }
                if (has3) {
                    const f32x4 bC1 = *(const f32x4*)(b1p + f0C + q*4);
                    half4 pC = *(const half4*)(pwp + f0C + q*4);
                    aC[rj] = bC1;
                    #pragma unroll
                    for (int i = 0; i < 4; ++i) aC[rj][i] += (float)pC[i];
                }
            }
            #pragma unroll
            for (int kst = 0; kst < 4; ++kst) {
                half8 wA = *(const half8*)(W1t + (f0A+ln)*128 + kst*32 + q*8);
                half8 wB = *(const half8*)(W1t + (f0B+ln)*128 + kst*32 + q*8);
                half8 wC;
                if (has3) wC = *(const half8*)(W1t + (f0C+ln)*128 + kst*32 + q*8);
                int kb = kst*4 + q;
                #pragma unroll
                for (int rj = 0; rj < 4; ++rj) {
                    int row = (rg*4 + rj)*16 + ln;
                    half8 bf = *(const half8*)(cmx + row*128 + ((kb ^ (row & 15))*8));
                    aA[rj] = MFMA(wA, bf, aA[rj]);
                    aB[rj] = MFMA(wB, bf, aB[rj]);
                    if (has3) aC[rj] = MFMA(wC, bf, aC[rj]);
                }
            }
            #pragma unroll
            for (int rj = 0; rj < 4; ++rj) {
                int row = (rg*4 + rj)*16 + ln;
                half4 hA, hB, hC;
                #pragma unroll
                for (int i = 0; i < 4; ++i) {
                    hA[i] = (_Float16)fmaxf(aA[rj][i], 0.f);
                    hB[i] = (_Float16)fmaxf(aB[rj][i], 0.f);
                }
                *(half4*)(hS + row*HSTR + f0A + q*4) = hA;
                *(half4*)(hS + row*HSTR + f0B + q*4) = hB;
                if (has3) {
                    #pragma unroll
                    for (int i = 0; i < 4; ++i) hC[i] = (_Float16)fmaxf(aC[rj][i], 0.f);
                    *(half4*)(hS + row*HSTR + f0C + q*4) = hC;
                }
            }
        }
        __syncthreads();                             // [B]

        // ---- L2': z2^T = W2^T @ h1^T, relu (held in regs until [C]) ----
        half4 h2A[4], h2B[4], h2C[4];
        {
            const f32x4 bA2 = *(const f32x4*)(b2p + f0A + q*4);
            const f32x4 bB2 = *(const f32x4*)(b2p + f0B + q*4);
            f32x4 aA[4], aB[4], aC[4];
            #pragma unroll
            for (int rj = 0; rj < 4; ++rj) {
                aA[rj] = bA2; aB[rj] = bB2;
                if (has3) aC[rj] = *(const f32x4*)(b2p + f0C + q*4);
            }
            #pragma unroll
            for (int kst = 0; kst < 5; ++kst) {
                half8 wA = *(const half8*)(W2t + (f0A+ln)*160 + kst*32 + q*8);
                half8 wB = *(const half8*)(W2t + (f0B+ln)*160 + kst*32 + q*8);
                half8 wC;
                if (has3) wC = *(const half8*)(W2t + (f0C+ln)*160 + kst*32 + q*8);
                #pragma unroll
                for (int rj = 0; rj < 4; ++rj) {
                    int row = (rg*4 + rj)*16 + ln;
                    half8 bf = *(const half8*)(hS + row*HSTR + kst*32 + q*8);
                    aA[rj] = MFMA(wA, bf, aA[rj]);
                    aB[rj] = MFMA(wB, bf, aB[rj]);
                    if (has3) aC[rj] = MFMA(wC, bf, aC[rj]);
                }
            }
            #pragma unroll
            for (int rj = 0; rj < 4; ++rj) {
                #pragma unroll
                for (int i = 0; i < 4; ++i) {
                    h2A[rj][i] = (_Float16)fmaxf(aA[rj][i], 0.f);
                    h2B[rj][i] = (_Float16)fmaxf(aB[rj][i], 0.f);
                    if (has3) h2C[rj][i] = (_Float16)fmaxf(aC[rj][i], 0.f);
                }
            }
        }
        __syncthreads();                             // [C] all h1 reads done
        #pragma unroll
        for (int rj = 0; rj < 4; ++rj) {
            int row = (rg*4 + rj)*16 + ln;
            *(half4*)(hS + row*HSTR + f0A + q*4) = h2A[rj];
            *(half4*)(hS + row*HSTR + f0B + q*4) = h2B[rj];
            if (has3) *(half4*)(hS + row*HSTR + f0C + q*4) = h2C[rj];
        }
        __syncthreads();                             // [D]

        // ---- L3': z3^T = W3^T @ h2^T; merge into register z-max ----
        {
            const f32x4 bz3 = *(const f32x4*)(b3 + og*16 + q*4);
            f32x4 z[4];
            #pragma unroll
            for (int rj = 0; rj < 4; ++rj) z[rj] = bz3;
            #pragma unroll
            for (int kst = 0; kst < 5; ++kst) {
                half8 wO = *(const half8*)(W3t + (og*16+ln)*160 + kst*32 + q*8);
                #pragma unroll
                for (int rj = 0; rj < 4; ++rj) {
                    int row = (rg3*4 + rj)*16 + ln;
                    half8 bf = *(const half8*)(hS + row*HSTR + kst*32 + q*8);
                    z[rj] = MFMA(wO, bf, z[rj]);
                }
            }
            // rows encode (j = rg3*2 + (rj>>1), b = (rj&1)*16 + ln); clamped
            // rows duplicate (s=127, same b) -> merge all unconditionally
            #pragma unroll
            for (int i = 0; i < 4; ++i) {
                rz0[i] = fmaxf(rz0[i], fmaxf(z[0][i], z[2][i]));
                rz1[i] = fmaxf(rz1[i], fmaxf(z[1][i], z[3][i]));
            }
        }
        __syncthreads();                             // protect hS/cmx for next item
    }

    // ---- final flush ----
    {
        float* scr = (float*)cmx;
        if (rg3 == 1) {
            *(f32x4*)(scr + (og*64 + lane)*8)     = rz0;
            *(f32x4*)(scr + (og*64 + lane)*8 + 4) = rz1;
        }
        __syncthreads();
        if (rg3 == 0) {
            f32x4 p0 = *(const f32x4*)(scr + (og*64 + lane)*8);
            f32x4 p1 = *(const f32x4*)(scr + (og*64 + lane)*8 + 4);
            #pragma unroll
            for (int i = 0; i < 4; ++i) {
                rz0[i] = fmaxf(rz0[i], p0[i]);
                rz1[i] = fmaxf(rz1[i], p1[i]);
            }
            int k = bid - bid_of(2*(cur_t >> 2)*(65 - (cur_t >> 2))
                                 + (cur_t - 4*(cur_t >> 2))*(32 - (cur_t >> 2)));
            float* sp = slots + ((size_t)cur_t*KSLOT + k)*2048;
            int o = og*16 + q*4;
            __builtin_nontemporal_store(rz0, (f32x4*)(sp + ln*64 + o));
            __builtin_nontemporal_store(rz1, (f32x4*)(sp + (16+ln)*64 + o));
        }
    }
}

extern "C" void kernel_launch(void* const* d_in, const int* in_sizes, int n_in,
                              void* d_out, int out_size, void* d_ws, size_t ws_size,
                              hipStream_t stream) {
    const float* P  = (const float*)d_in[0];
    const float* W1 = (const float*)d_in[1];
    const float* b1 = (const float*)d_in[2];
    const float* W2 = (const float*)d_in[3];
    const float* b2 = (const float*)d_in[4];
    const float* W3 = (const float*)d_in[5];
    const float* b3 = (const float*)d_in[6];

    tll_prep<<<240, 256, 0, stream>>>(P, W1, b1, W2, b2, W3, (char*)d_ws);

    hipFuncSetAttribute((const void*)tll_main,
                        hipFuncAttributeMaxDynamicSharedMemorySize, 75776);
    tll_main<<<256, 512, 75776, stream>>>(b3, (char*)d_ws);

    tll_finalize<<<128, 512, 0, stream>>>((const char*)d_ws, (float*)d_out);
}

// Round 8
// 220.817 us; speedup vs baseline: 1.6874x; 1.0635x over previous
//
#include <hip/hip_runtime.h>

// TemporalLogicLayer R8: 512 blocks -> 2 blocks/CU (barrier-drain overlap).
// out[b,t,o] = max_{s>=t} sigmoid(5*(relu(relu([cummax(P[t..s])|P[s]]W1+b1)W2+b2)W3+b3))
//
// R7 post-mortem: FETCH fixed (294->20 MB) but main stuck at 166 us with all
// pipes <15% busy: grid 256 = 1 block/CU, so every barrier drain idles the CU.
// R8: same structure, item ranges split over 512 blocks (4-5 items each) ->
// exactly 2 resident blocks/CU (LDS 75776 x2 = 148 KB < 160 KB), m114-style
// overlap of one block's barrier drain with the other's compute.
// - KSLOT 5->9 (a t now spans <=9 blocks); slots stored f16 (z-domain; err
//   dy = s'(a)|a|eps <= 2.2e-4 — negligible) to keep ws ~ R7 size.
// - everything else (flush-to-slots, register carry, transposed MFMA layers,
//   L2-resident W/PW/Pf) unchanged from R7.

#define TT 128
#define BB 32
#define DD 128
#define OO 64
#define NP 144
#define HSTR 168
#define KSLOT 9
#define NBLK 512

typedef __attribute__((ext_vector_type(8))) _Float16 half8;
typedef __attribute__((ext_vector_type(4))) _Float16 half4;
typedef __attribute__((ext_vector_type(4))) float f32x4;

// ws layout (bytes)
#define W1T_OFF 0                                   // f16 [144][128] (K<128 half)
#define W2T_OFF (W1T_OFF + 144*128*2)               // f16 [144][160]
#define W3T_OFF (W2T_OFF + 144*160*2)               // f16 [64][160]
#define B1P_OFF (W3T_OFF + 64*160*2)                // f32 [144]
#define B2P_OFF (B1P_OFF + 144*4)                   // f32 [144]
#define PW_OFF  (B2P_OFF + 144*4)                   // f16 [4096][144]
#define PF_OFF  (PW_OFF + 4096*144*2)               // f16 [32][128][128]
#define SLOT_OFF (PF_OFF + 32*128*128*2)            // f16 [128][KSLOT][32][64]

#define MFMA(A, B, C) __builtin_amdgcn_mfma_f32_16x16x32_f16((A), (B), (C), 0, 0, 0)

__device__ __forceinline__ half8 h8max(half8 a, half8 b) {
    half8 r;
    #pragma unroll
    for (int i = 0; i < 8; ++i) r[i] = (a[i] > b[i]) ? a[i] : b[i];
    return r;
}

// largest bid with range_start(bid) = (bid*33)>>3 <= it   (512-block partition)
__device__ __forceinline__ int bid_of(int it) {
    int bb = (8 * it) / 33;
    while ((((bb + 1) * 33) >> 3) <= it) ++bb;
    while (((bb * 33) >> 3) > it) --bb;
    return bb;
}

// ---------- prep (240 blocks x 256) ----------
__global__ void tll_prep(const float* __restrict__ P,
                         const float* __restrict__ W1, const float* __restrict__ b1,
                         const float* __restrict__ W2, const float* __restrict__ b2,
                         const float* __restrict__ W3, char* __restrict__ ws) {
    const int blk = blockIdx.x, tid = threadIdx.x;
    if (blk < 144) {
        _Float16* W1t = (_Float16*)(ws + W1T_OFF);
        _Float16* W2t = (_Float16*)(ws + W2T_OFF);
        _Float16* W3t = (_Float16*)(ws + W3T_OFF);
        float*    b1p = (float*)(ws + B1P_OFF);
        float*    b2p = (float*)(ws + B2P_OFF);
        int idx = blk * 256 + tid;
        if (idx < 144*128) {                        // W1t[n][k] = W1[k][n], k<128
            int n = idx >> 7, k = idx & 127;
            W1t[idx] = (_Float16)((n < 132) ? W1[k*132 + n] : 0.f);
        }
        if (idx < 144*160) {                        // W2t[n][k] = W2[k][n]
            int n = idx / 160, k = idx - n*160;
            W2t[idx] = (_Float16)((n < 132 && k < 132) ? W2[k*132 + n] : 0.f);
        }
        if (idx < 64*160) {                         // W3t[o][k] = W3[k][o]
            int o = idx / 160, k = idx - o*160;
            W3t[idx] = (_Float16)((k < 132) ? W3[k*64 + o] : 0.f);
        }
        if (idx < 144) {
            b1p[idx] = (idx < 132) ? b1[idx] : 0.f;
            b2p[idx] = (idx < 132) ? b2[idx] : 0.f;
        }
    } else if (blk < 208) {
        // PW[row][n] = P[row] @ W1[128:256, :], row = s*32+b
        _Float16* PW = (_Float16*)(ws + PW_OFF);
        const int blkp = blk - 144;
        const int w = tid >> 6, lane = tid & 63;
        const int ln = lane & 15, q = lane >> 4;
        const int row = (blkp*4 + w)*16 + ln;       // 0..4095
        const int b_ = row & 31, s_ = row >> 5;
        const float* pp = P + b_*(TT*DD) + s_*DD;
        half8 Bf[4];
        #pragma unroll
        for (int kst = 0; kst < 4; ++kst) {
            f32x4 p0 = *(const f32x4*)(pp + kst*32 + q*8);
            f32x4 p1 = *(const f32x4*)(pp + kst*32 + q*8 + 4);
            half8 h;
            #pragma unroll
            for (int i = 0; i < 4; ++i) { h[i] = (_Float16)p0[i]; h[4+i] = (_Float16)p1[i]; }
            Bf[kst] = h;
        }
        for (int mt = 0; mt < 9; ++mt) {
            f32x4 acc = (f32x4){0.f, 0.f, 0.f, 0.f};
            #pragma unroll
            for (int kst = 0; kst < 4; ++kst) {
                half8 A;                            // W1 rows 128+kst*32+q*8+i, col mt*16+ln
                const float* wp = W1 + (size_t)(128 + kst*32 + q*8)*132 + mt*16 + ln;
                #pragma unroll
                for (int i = 0; i < 8; ++i) A[i] = (_Float16)wp[i*132];
                acc = MFMA(A, Bf[kst], acc);
            }
            half4 hv;
            #pragma unroll
            for (int i = 0; i < 4; ++i) hv[i] = (_Float16)acc[i];
            *(half4*)(PW + (size_t)row*NP + mt*16 + q*4) = hv;
        }
    } else {
        // Pf[b] = f16(P[b])
        _Float16* Pf = (_Float16*)(ws + PF_OFF);
        const int b = blk - 208;
        const f32x4* src = (const f32x4*)(P + (size_t)b * TT * DD);
        half4* dst = (half4*)(Pf + (size_t)b * TT * DD);
        for (int i = tid; i < TT*DD/4; i += 256) {
            f32x4 v = src[i];
            half4 h;
            #pragma unroll
            for (int j = 0; j < 4; ++j) h[j] = (_Float16)v[j];
            dst[i] = h;
        }
    }
}

// ---------- finalize (128 blocks x 512): out = sigmoid(5 * max_k slots) ----------
__global__ void tll_finalize(const char* __restrict__ ws, float* __restrict__ out) {
    const int t = blockIdx.x, tid = threadIdx.x;
    const int g = t >> 2;
    const int it_s = 2*g*(65 - g) + (t - 4*g)*(32 - g);
    const int it_e = it_s + (32 - g);
    const int n = bid_of(it_e - 1) - bid_of(it_s) + 1;     // <= KSLOT
    const _Float16* slots = (const _Float16*)(ws + SLOT_OFF) + (size_t)t * KSLOT * 2048;
    const int cell = tid * 4;                              // 2048 cells: b*64+o
    half4 h = *(const half4*)(slots + cell);
    f32x4 v;
    #pragma unroll
    for (int i = 0; i < 4; ++i) v[i] = (float)h[i];
    for (int k = 1; k < n; ++k) {
        half4 u = *(const half4*)(slots + k*2048 + cell);
        #pragma unroll
        for (int i = 0; i < 4; ++i) v[i] = fmaxf(v[i], (float)u[i]);
    }
    f32x4 y;
    #pragma unroll
    for (int i = 0; i < 4; ++i) y[i] = 1.f / (1.f + __expf(-5.f * v[i]));
    const int b = cell >> 6, o = cell & 63;
    *(f32x4*)(out + (size_t)b*(TT*OO) + t*OO + o) = y;
}

// ---------- main ----------
__global__ __launch_bounds__(512, 4) void tll_main(
    const float* __restrict__ b3, char* __restrict__ ws)
{
    extern __shared__ char smem[];
    _Float16* hS  = (_Float16*)smem;                // [128][168] = 43008 B
    _Float16* cmx = hS + 128*HSTR;                  // [128][128] swizzled, 32768 B

    const _Float16* W1t = (const _Float16*)(ws + W1T_OFF);
    const _Float16* W2t = (const _Float16*)(ws + W2T_OFF);
    const _Float16* W3t = (const _Float16*)(ws + W3T_OFF);
    const float*    b1p = (const float*)(ws + B1P_OFF);
    const float*    b2p = (const float*)(ws + B2P_OFF);
    const _Float16* PW  = (const _Float16*)(ws + PW_OFF);
    const _Float16* Pf  = (const _Float16*)(ws + PF_OFF);
    _Float16*       slots = (_Float16*)(ws + SLOT_OFF);

    const int tid = threadIdx.x, w = tid >> 6, lane = tid & 63;
    const int ln = lane & 15, q = lane >> 4;
    const int fg = w >> 1, rg = w & 1;              // 4 f-groups x 2 r-groups
    const bool has3 = (fg == 0);                    // f-tiles (3,2,2,2) of 9
    const int fb = (fg == 0) ? 0 : (16 + 32*fg);    // 0,48,80,112
    const int f0A = fb, f0B = fb + 16, f0C = fb + 32;
    const int og = fg, rg3 = rg;                    // L3: o-tile, j-group

    // zero hS cols 144..159 (K padding read by L2'/L3'; avoid NaN garbage)
    for (int idx = tid; idx < 256; idx += 512) {
        int row = idx >> 1, hv = idx & 1;
        half8 z;
        #pragma unroll
        for (int i = 0; i < 8; ++i) z[i] = (_Float16)0.f;
        *(half8*)(hS + row*HSTR + 144 + hv*8) = z;
    }

    const int sb = tid >> 4, dblk = tid & 15, d0 = dblk*8;  // staging role
    const _Float16* pfb = Pf + (size_t)sb*(TT*DD) + d0;

    const int bid = blockIdx.x;
    int it = (bid*33) >> 3;                          // contiguous t-major ranges
    const int hi = ((bid + 1)*33) >> 3;

    int cur_t = -1;
    f32x4 rz0 = (f32x4){-1e30f,-1e30f,-1e30f,-1e30f};  // z-domain max, b=ln
    f32x4 rz1 = rz0;                                    // b=16+ln
    half8 mi;                                           // carried cummax Pf[b,t..s0-1,d]
    __syncthreads();

    for (; it < hi; ++it) {
        // ---- decode item -> (t, c) ----
        int g = (int)((65.0f - sqrtf((float)(4225 - 2*it))) * 0.5f);
        if (g < 0) g = 0; if (g > 31) g = 31;
        while (g > 0 && 2*g*(65 - g) > it) --g;
        while (2*(g+1)*(65 - (g+1)) <= it) ++g;
        int rem = it - 2*g*(65 - g);
        int ntc = 32 - g;
        int t  = 4*g + rem/ntc;
        int c  = rem - (rem/ntc)*ntc;
        int s0 = t + 4*c;

        // ---- t-change: flush z-max to slot, reset + scan-init carry ----
        if (t != cur_t) {                            // block-uniform branch
            if (cur_t >= 0) {
                float* scr = (float*)cmx;            // cmx is dead here
                if (rg3 == 1) {
                    *(f32x4*)(scr + (og*64 + lane)*8)     = rz0;
                    *(f32x4*)(scr + (og*64 + lane)*8 + 4) = rz1;
                }
                __syncthreads();
                if (rg3 == 0) {
                    f32x4 p0 = *(const f32x4*)(scr + (og*64 + lane)*8);
                    f32x4 p1 = *(const f32x4*)(scr + (og*64 + lane)*8 + 4);
                    #pragma unroll
                    for (int i = 0; i < 4; ++i) {
                        rz0[i] = fmaxf(rz0[i], p0[i]);
                        rz1[i] = fmaxf(rz1[i], p1[i]);
                    }
                    int k = bid - bid_of(2*(cur_t >> 2)*(65 - (cur_t >> 2))
                                         + (cur_t - 4*(cur_t >> 2))*(32 - (cur_t >> 2)));
                    _Float16* sp = slots + ((size_t)cur_t*KSLOT + k)*2048;
                    int o = og*16 + q*4;
                    half4 z0, z1;
                    #pragma unroll
                    for (int i = 0; i < 4; ++i) { z0[i] = (_Float16)rz0[i]; z1[i] = (_Float16)rz1[i]; }
                    __builtin_nontemporal_store(z0, (half4*)(sp + ln*64 + o));
                    __builtin_nontemporal_store(z1, (half4*)(sp + (16+ln)*64 + o));
                }
                __syncthreads();                     // protect scr before staging
            }
            cur_t = t;
            rz0 = (f32x4){-1e30f,-1e30f,-1e30f,-1e30f};
            rz1 = rz0;
            #pragma unroll
            for (int i = 0; i < 8; ++i) mi[i] = (_Float16)(-65504.0f);
            for (int s = t; s < s0; ++s)             // nonempty only at block start
                mi = h8max(mi, *(const half8*)(pfb + s*DD));
        }

        // ---- stage cmx: fold 4 steps onto carried mi ----
        #pragma unroll
        for (int j = 0; j < 4; ++j) {
            int s = s0 + j; if (s > 127) s = 127;    // dup of valid s=127, same b;
            mi = h8max(mi, *(const half8*)(pfb + s*DD)); // only in t's last chunk
            int row = j*32 + sb;
            *(half8*)(cmx + row*128 + ((dblk ^ (row & 15))*8)) = mi;
        }
        __syncthreads();                             // [A]

        // ---- L1': z1^T = W1a^T @ cmx^T, init = PW + b1, relu -> hS ----
        {
            const f32x4 bA1 = *(const f32x4*)(b1p + f0A + q*4);
            const f32x4 bB1 = *(const f32x4*)(b1p + f0B + q*4);
            f32x4 aA[4], aB[4], aC[4];
            #pragma unroll
            for (int rj = 0; rj < 4; ++rj) {
                int row = (rg*4 + rj)*16 + ln;           // j = row>>5, b = row&31
                int sj = s0 + (row >> 5);                // clamp s ONLY, preserve b
                if (sj > 127) sj = 127;
                int rowg = sj*32 + (row & 31);
                const _Float16* pwp = PW + (size_t)rowg*NP;
                half4 pA = *(const half4*)(pwp + f0A + q*4);
                half4 pB = *(const half4*)(pwp + f0B + q*4);
                aA[rj] = bA1; aB[rj] = bB1;
                #pragma unroll
                for (int i = 0; i < 4; ++i) { aA[rj][i] += (float)pA[i]; aB[rj][i] += (float)pB[i]; }
                if (has3) {
                    const f32x4 bC1 = *(const f32x4*)(b1p + f0C + q*4);
                    half4 pC = *(const half4*)(pwp + f0C + q*4);
                    aC[rj] = bC1;
                    #pragma unroll
                    for (int i = 0; i < 4; ++i) aC[rj][i] += (float)pC[i];
                }
            }
            #pragma unroll
            for (int kst = 0; kst < 4; ++kst) {
                half8 wA = *(const half8*)(W1t + (f0A+ln)*128 + kst*32 + q*8);
                half8 wB = *(const half8*)(W1t + (f0B+ln)*128 + kst*32 + q*8);
                half8 wC;
                if (has3) wC = *(const half8*)(W1t + (f0C+ln)*128 + kst*32 + q*8);
                int kb = kst*4 + q;
                #pragma unroll
                for (int rj = 0; rj < 4; ++rj) {
                    int row = (rg*4 + rj)*16 + ln;
                    half8 bf = *(const half8*)(cmx + row*128 + ((kb ^ (row & 15))*8));
                    aA[rj] = MFMA(wA, bf, aA[rj]);
                    aB[rj] = MFMA(wB, bf, aB[rj]);
                    if (has3) aC[rj] = MFMA(wC, bf, aC[rj]);
                }
            }
            #pragma unroll
            for (int rj = 0; rj < 4; ++rj) {
                int row = (rg*4 + rj)*16 + ln;
                half4 hA, hB, hC;
                #pragma unroll
                for (int i = 0; i < 4; ++i) {
                    hA[i] = (_Float16)fmaxf(aA[rj][i], 0.f);
                    hB[i] = (_Float16)fmaxf(aB[rj][i], 0.f);
                }
                *(half4*)(hS + row*HSTR + f0A + q*4) = hA;
                *(half4*)(hS + row*HSTR + f0B + q*4) = hB;
                if (has3) {
                    #pragma unroll
                    for (int i = 0; i < 4; ++i) hC[i] = (_Float16)fmaxf(aC[rj][i], 0.f);
                    *(half4*)(hS + row*HSTR + f0C + q*4) = hC;
                }
            }
        }
        __syncthreads();                             // [B]

        // ---- L2': z2^T = W2^T @ h1^T, relu (held in regs until [C]) ----
        half4 h2A[4], h2B[4], h2C[4];
        {
            const f32x4 bA2 = *(const f32x4*)(b2p + f0A + q*4);
            const f32x4 bB2 = *(const f32x4*)(b2p + f0B + q*4);
            f32x4 aA[4], aB[4], aC[4];
            #pragma unroll
            for (int rj = 0; rj < 4; ++rj) {
                aA[rj] = bA2; aB[rj] = bB2;
                if (has3) aC[rj] = *(const f32x4*)(b2p + f0C + q*4);
            }
            #pragma unroll
            for (int kst = 0; kst < 5; ++kst) {
                half8 wA = *(const half8*)(W2t + (f0A+ln)*160 + kst*32 + q*8);
                half8 wB = *(const half8*)(W2t + (f0B+ln)*160 + kst*32 + q*8);
                half8 wC;
                if (has3) wC = *(const half8*)(W2t + (f0C+ln)*160 + kst*32 + q*8);
                #pragma unroll
                for (int rj = 0; rj < 4; ++rj) {
                    int row = (rg*4 + rj)*16 + ln;
                    half8 bf = *(const half8*)(hS + row*HSTR + kst*32 + q*8);
                    aA[rj] = MFMA(wA, bf, aA[rj]);
                    aB[rj] = MFMA(wB, bf, aB[rj]);
                    if (has3) aC[rj] = MFMA(wC, bf, aC[rj]);
                }
            }
            #pragma unroll
            for (int rj = 0; rj < 4; ++rj) {
                #pragma unroll
                for (int i = 0; i < 4; ++i) {
                    h2A[rj][i] = (_Float16)fmaxf(aA[rj][i], 0.f);
                    h2B[rj][i] = (_Float16)fmaxf(aB[rj][i], 0.f);
                    if (has3) h2C[rj][i] = (_Float16)fmaxf(aC[rj][i], 0.f);
                }
            }
        }
        __syncthreads();                             // [C] all h1 reads done
        #pragma unroll
        for (int rj = 0; rj < 4; ++rj) {
            int row = (rg*4 + rj)*16 + ln;
            *(half4*)(hS + row*HSTR + f0A + q*4) = h2A[rj];
            *(half4*)(hS + row*HSTR + f0B + q*4) = h2B[rj];
            if (has3) *(half4*)(hS + row*HSTR + f0C + q*4) = h2C[rj];
        }
        __syncthreads();                             // [D]

        // ---- L3': z3^T = W3^T @ h2^T; merge into register z-max ----
        {
            const f32x4 bz3 = *(const f32x4*)(b3 + og*16 + q*4);
            f32x4 z[4];
            #pragma unroll
            for (int rj = 0; rj < 4; ++rj) z[rj] = bz3;
            #pragma unroll
            for (int kst = 0; kst < 5; ++kst) {
                half8 wO = *(const half8*)(W3t + (og*16+ln)*160 + kst*32 + q*8);
                #pragma unroll
                for (int rj = 0; rj < 4; ++rj) {
                    int row = (rg3*4 + rj)*16 + ln;
                    half8 bf = *(const half8*)(hS + row*HSTR + kst*32 + q*8);
                    z[rj] = MFMA(wO, bf, z[rj]);
                }
            }
            // rows encode (j = rg3*2 + (rj>>1), b = (rj&1)*16 + ln); clamped
            // rows duplicate (s=127, same b) -> merge all unconditionally
            #pragma unroll
            for (int i = 0; i < 4; ++i) {
                rz0[i] = fmaxf(rz0[i], fmaxf(z[0][i], z[2][i]));
                rz1[i] = fmaxf(rz1[i], fmaxf(z[1][i], z[3][i]));
            }
        }
        __syncthreads();                             // protect hS/cmx for next item
    }

    // ---- final flush ----
    {
        float* scr = (float*)cmx;
        if (rg3 == 1) {
            *(f32x4*)(scr + (og*64 + lane)*8)     = rz0;
            *(f32x4*)(scr + (og*64 + lane)*8 + 4) = rz1;
        }
        __syncthreads();
        if (rg3 == 0) {
            f32x4 p0 = *(const f32x4*)(scr + (og*64 + lane)*8);
            f32x4 p1 = *(const f32x4*)(scr + (og*64 + lane)*8 + 4);
            #pragma unroll
            for (int i = 0; i < 4; ++i) {
                rz0[i] = fmaxf(rz0[i], p0[i]);
                rz1[i] = fmaxf(rz1[i], p1[i]);
            }
            int k = bid - bid_of(2*(cur_t >> 2)*(65 - (cur_t >> 2))
                                 + (cur_t - 4*(cur_t >> 2))*(32 - (cur_t >> 2)));
            _Float16* sp = slots + ((size_t)cur_t*KSLOT + k)*2048;
            int o = og*16 + q*4;
            half4 z0, z1;
            #pragma unroll
            for (int i = 0; i < 4; ++i) { z0[i] = (_Float16)rz0[i]; z1[i] = (_Float16)rz1[i]; }
            __builtin_nontemporal_store(z0, (half4*)(sp + ln*64 + o));
            __builtin_nontemporal_store(z1, (half4*)(sp + (16+ln)*64 + o));
        }
    }
}

extern "C" void kernel_launch(void* const* d_in, const int* in_sizes, int n_in,
                              void* d_out, int out_size, void* d_ws, size_t ws_size,
                              hipStream_t stream) {
    const float* P  = (const float*)d_in[0];
    const float* W1 = (const float*)d_in[1];
    const float* b1 = (const float*)d_in[2];
    const float* W2 = (const float*)d_in[3];
    const float* b2 = (const float*)d_in[4];
    const float* W3 = (const float*)d_in[5];
    const float* b3 = (const float*)d_in[6];

    tll_prep<<<240, 256, 0, stream>>>(P, W1, b1, W2, b2, W3, (char*)d_ws);

    hipFuncSetAttribute((const void*)tll_main,
                        hipFuncAttributeMaxDynamicSharedMemorySize, 75776);
    tll_main<<<NBLK, 512, 75776, stream>>>(b3, (char*)d_ws);

    tll_finalize<<<128, 512, 0, stream>>>((const char*)d_ws, (float*)d_out);
}